// Round 5
// baseline (46.398 us; speedup 1.0000x reference)
//
#include <hip/hip_runtime.h>

// x: [B, W, C] fp32; out: [B, C] fp32
// out[b,c] = mean_w x[b,w,c] + (sum_w (w - tm) * x[b,w,c] / denom) * (tpred - tm)
// tm = (W-1)/2, denom = W(W^2-1)/12, tpred = W + horizon - 1.
//
// Ladder: R1 (2 cols/thread, float2, runtime loop) 36.1 us = 5.78 TB/s.
//         R2 (4 cols/thread, full unroll) 50.7 us REGRESSION (TLP halved).
//         R3 (R1 + compile-time W, unroll 8) 37.9 us (ILP neutral; TLP-saturated).
// R5: R1 structure + nontemporal loads/stores (read-once 205 MB stream; skip
//     L2 fill/evict churn). Native ext_vector_type for the builtin (HIP's
//     float2 wrapper class is rejected). C == 2 (mod 4): 8B max aligned width.

typedef float f32x2 __attribute__((ext_vector_type(2)));

__global__ void __launch_bounds__(256) linfit_ols_nt(
    const float* __restrict__ x, const int* __restrict__ horp,
    float* __restrict__ out, int B, int C, int W) {
    const int pairs = (C + 1) >> 1;            // 2 columns per thread
    const int total = B * pairs;
    const int i = blockIdx.x * blockDim.x + threadIdx.x;
    if (i >= total) return;

    const int b = i / pairs;
    const int p = i - b * pairs;
    const int c = p * 2;

    const float tm = 0.5f * (float)(W - 1);
    const float* px = x + (size_t)b * (size_t)W * (size_t)C + c;

    float s0 = 0.f, s1 = 0.f;   // sum y
    float d0 = 0.f, d1 = 0.f;   // sum (t - tm) * y

    if (c + 1 < C) {
        for (int w = 0; w < W; ++w) {
            f32x2 v = __builtin_nontemporal_load(
                reinterpret_cast<const f32x2*>(px + (size_t)w * (size_t)C));
            const float tc = (float)w - tm;
            s0 += v.x; s1 += v.y;
            d0 = fmaf(tc, v.x, d0); d1 = fmaf(tc, v.y, d1);
        }
    } else {
        for (int w = 0; w < W; ++w) {
            float v = __builtin_nontemporal_load(px + (size_t)w * (size_t)C);
            const float tc = (float)w - tm;
            s0 += v; d0 = fmaf(tc, v, d0);
        }
    }

    const int H = *horp;                        // uniform scalar read
    const float Wf = (float)W;
    const float denom = Wf * (Wf * Wf - 1.0f) * (1.0f / 12.0f);
    const float tpred = (float)(W + H - 1);
    const float scale = (tpred - tm) / denom;
    const float invW = 1.0f / Wf;

    float* po = out + (size_t)b * (size_t)C + c;
    const float r0 = s0 * invW + d0 * scale;
    if (c + 1 < C) {
        f32x2 r; r.x = r0; r.y = s1 * invW + d1 * scale;
        __builtin_nontemporal_store(r, reinterpret_cast<f32x2*>(po));
    } else {
        __builtin_nontemporal_store(r0, po);
    }
}

extern "C" void kernel_launch(void* const* d_in, const int* in_sizes, int n_in,
                              void* d_out, int out_size, void* d_ws, size_t ws_size,
                              hipStream_t stream) {
    const float* x = (const float*)d_in[0];
    const int* horp = (const int*)d_in[2];
    float* out = (float*)d_out;

    const int C = 3142;                    // from reference setup (not derivable from flat sizes)
    const int B = out_size / C;            // 256
    const int W = in_sizes[0] / out_size;  // 64

    const int pairs = (C + 1) / 2;
    const int total = B * pairs;
    const int block = 256;
    const int grid = (total + block - 1) / block;

    linfit_ols_nt<<<grid, block, 0, stream>>>(x, horp, out, B, C, W);
}

// Round 6
// 36.163 us; speedup vs baseline: 1.2830x; 1.2830x over previous
//
#include <hip/hip_runtime.h>

// x: [B, W, C] fp32; out: [B, C] fp32
// out[b,c] = mean_w x[b,w,c] + (sum_w (w - tm) * x[b,w,c] / denom) * (tpred - tm)
// tm = (W-1)/2, denom = W(W^2-1)/12, tpred = W + horizon - 1.
//
// Ladder: R1 (2 cols/thread, float2, runtime loop) 36.1 us = 5.78 TB/s  <= BEST
//         R2 (4 cols/thread, full unroll)   50.7 us  (TLP halved + VGPR bloat)
//         R3 (R1 + compile-time W, unroll8) 37.9 us  (ILP neutral; TLP-saturated)
//         R5 (R1 + nontemporal ld/st)       46.4 us  (nt bypasses L3; input is
//                                                     L3-resident under replay)
// R6: exact revert to R1. 36 us ~= 92% of the ~6.3 TB/s read ceiling; with
// ~2 us launch overhead this is the memory roofline for a 205 MB read stream.
// C = 3142 == 2 (mod 4): float2 (8 B/lane) is the max safe aligned width.

__global__ void linfit_ols_kernel(const float* __restrict__ x,
                                  const int* __restrict__ horp,
                                  float* __restrict__ out,
                                  int B, int C, int W) {
    const int pairs = (C + 1) >> 1;            // threads per batch row (2 cols each)
    const int total = B * pairs;
    const int i = blockIdx.x * blockDim.x + threadIdx.x;
    if (i >= total) return;

    const int b = i / pairs;
    const int p = i - b * pairs;
    const int c = p * 2;

    const float tm = 0.5f * (float)(W - 1);
    const float* px = x + (size_t)b * (size_t)W * (size_t)C + c;

    float s0 = 0.f, s1 = 0.f;   // sum y
    float d0 = 0.f, d1 = 0.f;   // sum (t - tm) * y

    if (c + 1 < C) {
        for (int w = 0; w < W; ++w) {
            // 8B-aligned: C even, c even => element offset even
            float2 v = *reinterpret_cast<const float2*>(px + (size_t)w * (size_t)C);
            const float tc = (float)w - tm;
            s0 += v.x;
            s1 += v.y;
            d0 = fmaf(tc, v.x, d0);
            d1 = fmaf(tc, v.y, d1);
        }
    } else {
        for (int w = 0; w < W; ++w) {
            float v = px[(size_t)w * (size_t)C];
            const float tc = (float)w - tm;
            s0 += v;
            d0 = fmaf(tc, v, d0);
        }
    }

    const int H = *horp;                        // uniform scalar read
    const float Wf = (float)W;
    const float denom = Wf * (Wf * Wf - 1.0f) * (1.0f / 12.0f);
    const float tpred = (float)(W + H - 1);
    const float scale = (tpred - tm) / denom;
    const float invW = 1.0f / Wf;

    float* po = out + (size_t)b * (size_t)C + c;
    po[0] = s0 * invW + d0 * scale;
    if (c + 1 < C) po[1] = s1 * invW + d1 * scale;
}

extern "C" void kernel_launch(void* const* d_in, const int* in_sizes, int n_in,
                              void* d_out, int out_size, void* d_ws, size_t ws_size,
                              hipStream_t stream) {
    const float* x = (const float*)d_in[0];
    const int* horp = (const int*)d_in[2];     // d_in[1] = window (derived on host), d_in[2] = horizon
    float* out = (float*)d_out;

    const int C = 3142;                    // from reference setup (not derivable from flat sizes)
    const int B = out_size / C;            // 256
    const int W = in_sizes[0] / out_size;  // 64

    const int pairs = (C + 1) / 2;
    const int total = B * pairs;
    const int block = 256;
    const int grid = (total + block - 1) / block;

    linfit_ols_kernel<<<grid, block, 0, stream>>>(x, horp, out, B, C, W);
}